// Round 1
// baseline (826.491 us; speedup 1.0000x reference)
//
#include <hip/hip_runtime.h>
#include <hip/hip_bf16.h>

// Problem constants
#define SCALE_ 0.125f

// Workspace layout (in floats)
#define Q_OFF  0
#define K_OFF  3145728
#define V_OFF  6291456
#define RH_OFF 9437184
#define RW_OFF 11010048
#define AO_OFF 12582912
// total = 15728640 floats = 62.9 MB

// ---------------------------------------------------------------------------
// Kernel 1: QKV GEMM  [8192,384] @ [384,1152] + bias -> scatter to q/k/v
// q/k/v layout: [g=48][hw=1024][d=64], g = b*6 + head
// ---------------------------------------------------------------------------
__global__ __launch_bounds__(256) void qkv_gemm(const float* __restrict__ x,
        const float* __restrict__ w, const float* __restrict__ bias,
        float* __restrict__ ws) {
    __shared__ float As[64][33];
    __shared__ float Bs[32][65];
    const int t = threadIdx.x;
    const int ty = t >> 4, tx = t & 15;
    const int row0 = blockIdx.y * 64, col0 = blockIdx.x * 64;
    float acc[4][4] = {};
    for (int kb = 0; kb < 384; kb += 32) {
#pragma unroll
        for (int i = 0; i < 2; ++i) {
            int idx = t + i * 256;              // 0..511
            int r = idx >> 3, c4 = idx & 7;     // 64 rows x 8 float4
            float4 vv = *(const float4*)&x[(row0 + r) * 384 + kb + c4 * 4];
            As[r][c4*4+0] = vv.x; As[r][c4*4+1] = vv.y;
            As[r][c4*4+2] = vv.z; As[r][c4*4+3] = vv.w;
        }
#pragma unroll
        for (int i = 0; i < 2; ++i) {
            int idx = t + i * 256;
            int r = idx >> 4, c4 = idx & 15;    // 32 rows x 16 float4
            float4 vv = *(const float4*)&w[(kb + r) * 1152 + col0 + c4 * 4];
            Bs[r][c4*4+0] = vv.x; Bs[r][c4*4+1] = vv.y;
            Bs[r][c4*4+2] = vv.z; Bs[r][c4*4+3] = vv.w;
        }
        __syncthreads();
#pragma unroll
        for (int kk = 0; kk < 32; ++kk) {
            float a[4], b[4];
#pragma unroll
            for (int i2 = 0; i2 < 4; ++i2) a[i2] = As[ty*4+i2][kk];
#pragma unroll
            for (int j = 0; j < 4; ++j) b[j] = Bs[kk][tx*4+j];
#pragma unroll
            for (int i2 = 0; i2 < 4; ++i2)
#pragma unroll
                for (int j = 0; j < 4; ++j)
                    acc[i2][j] = fmaf(a[i2], b[j], acc[i2][j]);
        }
        __syncthreads();
    }
#pragma unroll
    for (int i2 = 0; i2 < 4; ++i2) {
        int m = row0 + ty*4 + i2;
        int b = m >> 10, hw = m & 1023;
#pragma unroll
        for (int j = 0; j < 4; ++j) {
            int n = col0 + tx*4 + j;
            float val = acc[i2][j] + bias[n];
            int tsel = n / 384;
            int rem = n - tsel * 384;
            int head = rem >> 6, d = rem & 63;
            int g = b * 6 + head;
            ws[tsel * 3145728 + g * 65536 + hw * 64 + d] = val;
        }
    }
}

// ---------------------------------------------------------------------------
// Kernel 2: rel_h / rel_w.  mode 0: block (g, h) -> rel_h[g,h,:,:]
//                           mode 1: block (g, w) -> rel_w[g,:,w,:]
// rel layout: [(g*1024 + h*32 + w)*32 + idx]
// ---------------------------------------------------------------------------
__global__ __launch_bounds__(256) void rel_kernel(const float* __restrict__ q,
        const float* __restrict__ rph, const float* __restrict__ rpw,
        float* __restrict__ relh, float* __restrict__ relw) {
    __shared__ float ql[32][65];
    __shared__ float Rl[32][65];
    const int g = blockIdx.x;
    const int pos = blockIdx.y;
    const int mode = blockIdx.z;
    const int t = threadIdx.x;
    const float* rp = (mode == 0) ? rph : rpw;
    for (int i = t; i < 2048; i += 256) {
        int r = i >> 6, d = i & 63;
        int hw = (mode == 0) ? (pos * 32 + r) : (r * 32 + pos);
        ql[r][d] = q[(g * 1024 + hw) * 64 + d];
    }
    for (int i = t; i < 2048; i += 256) {
        int r = i >> 6, d = i & 63;
        Rl[r][d] = rp[(pos - r + 31) * 64 + d];
    }
    __syncthreads();
#pragma unroll
    for (int i = 0; i < 4; ++i) {
        int o = t + i * 256;                    // 0..1023
        int other = o >> 5, idx = o & 31;
        float s = 0.f;
#pragma unroll
        for (int d = 0; d < 64; ++d)
            s = fmaf(ql[other][d], Rl[idx][d], s);
        if (mode == 0)
            relh[(g * 1024 + pos * 32 + other) * 32 + idx] = s;
        else
            relw[(g * 1024 + other * 32 + pos) * 32 + idx] = s;
    }
}

// ---------------------------------------------------------------------------
// Kernel 3: flash attention per (head g, 64-row q-block)
// ---------------------------------------------------------------------------
__global__ __launch_bounds__(256) void attn_kernel(const float* __restrict__ ws_q,
        const float* __restrict__ ws_k, const float* __restrict__ ws_v,
        const float* __restrict__ relh, const float* __restrict__ relw,
        float* __restrict__ attout) {
    __shared__ float Qs[64][65];
    __shared__ float Ks[64][65];
    __shared__ float Vs[64][65];
    __shared__ float Ps[64][65];
    const int g = blockIdx.x;
    const int q0 = blockIdx.y * 64;
    const int t = threadIdx.x;
    const int qi = t >> 2, part = t & 3;
    for (int i = t; i < 4096; i += 256) {
        int r = i >> 6, d = i & 63;
        Qs[r][d] = ws_q[(g * 1024 + q0 + r) * 64 + d] * SCALE_;
    }
    float O[16];
#pragma unroll
    for (int j = 0; j < 16; ++j) O[j] = 0.f;
    float mrow = -1e30f, lrow = 0.f;
    const int qrow = g * 1024 + q0 + qi;
    for (int kb = 0; kb < 16; ++kb) {
        for (int i = t; i < 4096; i += 256) {
            int r = i >> 6, d = i & 63;
            Ks[r][d] = ws_k[(g * 1024 + kb * 64 + r) * 64 + d];
            Vs[r][d] = ws_v[(g * 1024 + kb * 64 + r) * 64 + d];
        }
        __syncthreads();
        float s[16];
        float rh = relh[qrow * 32 + kb * 2 + (part >> 1)];
#pragma unroll
        for (int j = 0; j < 16; ++j)
            s[j] = rh + relw[qrow * 32 + ((part * 16 + j) & 31)];
        for (int d = 0; d < 64; ++d) {
            float qv = Qs[qi][d];
#pragma unroll
            for (int j = 0; j < 16; ++j)
                s[j] = fmaf(qv, Ks[part * 16 + j][d], s[j]);
        }
        float smax = s[0];
#pragma unroll
        for (int j = 1; j < 16; ++j) smax = fmaxf(smax, s[j]);
        smax = fmaxf(smax, __shfl_xor(smax, 1));
        smax = fmaxf(smax, __shfl_xor(smax, 2));
        float mnew = fmaxf(mrow, smax);
        float corr = __expf(mrow - mnew);
        float psum = 0.f;
#pragma unroll
        for (int j = 0; j < 16; ++j) { s[j] = __expf(s[j] - mnew); psum += s[j]; }
        psum += __shfl_xor(psum, 1);
        psum += __shfl_xor(psum, 2);
        lrow = lrow * corr + psum;
        mrow = mnew;
#pragma unroll
        for (int j = 0; j < 16; ++j) { O[j] *= corr; Ps[qi][part * 16 + j] = s[j]; }
        __syncthreads();
        for (int kj = 0; kj < 64; ++kj) {
            float pp = Ps[qi][kj];
#pragma unroll
            for (int j = 0; j < 16; ++j)
                O[j] = fmaf(pp, Vs[kj][part * 16 + j], O[j]);
        }
        __syncthreads();
    }
    float inv = 1.f / lrow;
#pragma unroll
    for (int j = 0; j < 16; ++j)
        attout[qrow * 64 + part * 16 + j] = O[j] * inv;
}

// ---------------------------------------------------------------------------
// Kernel 4: output projection [8192,384] @ [384,384] + bias -> d_out
// A gathered from attout [g][hw][d] with c = head*64+d
// ---------------------------------------------------------------------------
__global__ __launch_bounds__(256) void proj_gemm(const float* __restrict__ att,
        const float* __restrict__ w, const float* __restrict__ bias,
        float* __restrict__ out) {
    __shared__ float As[64][33];
    __shared__ float Bs[32][65];
    const int t = threadIdx.x;
    const int ty = t >> 4, tx = t & 15;
    const int row0 = blockIdx.y * 64, col0 = blockIdx.x * 64;
    float acc[4][4] = {};
    for (int kb = 0; kb < 384; kb += 32) {
#pragma unroll
        for (int i = 0; i < 2; ++i) {
            int idx = t + i * 256;
            int r = idx >> 3, c4 = idx & 7;
            int m = row0 + r;
            int b = m >> 10, hw = m & 1023;
            int cbase = kb + c4 * 4;
            int head = cbase >> 6, d = cbase & 63;
            float4 vv = *(const float4*)&att[(b * 6 + head) * 65536 + hw * 64 + d];
            As[r][c4*4+0] = vv.x; As[r][c4*4+1] = vv.y;
            As[r][c4*4+2] = vv.z; As[r][c4*4+3] = vv.w;
        }
#pragma unroll
        for (int i = 0; i < 2; ++i) {
            int idx = t + i * 256;
            int r = idx >> 4, c4 = idx & 15;
            float4 vv = *(const float4*)&w[(kb + r) * 384 + col0 + c4 * 4];
            Bs[r][c4*4+0] = vv.x; Bs[r][c4*4+1] = vv.y;
            Bs[r][c4*4+2] = vv.z; Bs[r][c4*4+3] = vv.w;
        }
        __syncthreads();
#pragma unroll
        for (int kk = 0; kk < 32; ++kk) {
            float a[4], b[4];
#pragma unroll
            for (int i2 = 0; i2 < 4; ++i2) a[i2] = As[ty*4+i2][kk];
#pragma unroll
            for (int j = 0; j < 4; ++j) b[j] = Bs[kk][tx*4+j];
#pragma unroll
            for (int i2 = 0; i2 < 4; ++i2)
#pragma unroll
                for (int j = 0; j < 4; ++j)
                    acc[i2][j] = fmaf(a[i2], b[j], acc[i2][j]);
        }
        __syncthreads();
    }
#pragma unroll
    for (int i2 = 0; i2 < 4; ++i2) {
        int m = row0 + ty*4 + i2;
#pragma unroll
        for (int j = 0; j < 4; ++j) {
            int n = col0 + tx*4 + j;
            out[m * 384 + n] = acc[i2][j] + bias[n];
        }
    }
}

extern "C" void kernel_launch(void* const* d_in, const int* in_sizes, int n_in,
                              void* d_out, int out_size, void* d_ws, size_t ws_size,
                              hipStream_t stream) {
    const float* x      = (const float*)d_in[0];
    const float* qkv_w  = (const float*)d_in[1];
    const float* qkv_b  = (const float*)d_in[2];
    const float* proj_w = (const float*)d_in[3];
    const float* proj_b = (const float*)d_in[4];
    const float* rph    = (const float*)d_in[5];
    const float* rpw    = (const float*)d_in[6];
    float* out = (float*)d_out;
    float* ws  = (float*)d_ws;

    qkv_gemm<<<dim3(18, 128), 256, 0, stream>>>(x, qkv_w, qkv_b, ws);
    rel_kernel<<<dim3(48, 32, 2), 256, 0, stream>>>(ws + Q_OFF, rph, rpw,
                                                    ws + RH_OFF, ws + RW_OFF);
    attn_kernel<<<dim3(48, 16), 256, 0, stream>>>(ws + Q_OFF, ws + K_OFF, ws + V_OFF,
                                                  ws + RH_OFF, ws + RW_OFF, ws + AO_OFF);
    proj_gemm<<<dim3(6, 128), 256, 0, stream>>>(ws + AO_OFF, proj_w, proj_b, out);
}

// Round 2
// 184.648 us; speedup vs baseline: 4.4760x; 4.4760x over previous
//
#include <hip/hip_runtime.h>

typedef __attribute__((ext_vector_type(8))) short bf16x8;
typedef __attribute__((ext_vector_type(4))) float f32x4;

#define MFMA(a, b, c) __builtin_amdgcn_mfma_f32_16x16x32_bf16((a), (b), (c), 0, 0, 0)

__device__ __forceinline__ unsigned short f2bf(float f) {
    union { float f; unsigned u; } v; v.f = f;
    unsigned r = v.u + 0x7FFFu + ((v.u >> 16) & 1u);
    return (unsigned short)(r >> 16);
}
__device__ __forceinline__ float bf2f(unsigned short h) {
    union { unsigned u; float f; } v; v.u = ((unsigned)h) << 16;
    return v.f;
}

// ---------------------------------------------------------------------------
// Workspace layout (bytes). ATT arrays reuse the X region (x consumed before
// attn writes).
// ---------------------------------------------------------------------------
#define WS_QHI   0
#define WS_QLO   6291456
#define WS_KHI   12582912
#define WS_KLO   18874368
#define WS_VTHI  25165824
#define WS_VTLO  31457280
#define WS_RELH  37748736
#define WS_RELW  40894464
#define WS_WTH   44040192
#define WS_WTL   44924928
#define WS_PWTH  45809664
#define WS_PWTL  46104576
#define WS_XHI   46399488
#define WS_XLO   52690944
// end 58982400 bytes (56.25 MB)

// ---------------------------------------------------------------------------
// Prep: split fp32 -> bf16 hi/lo
// ---------------------------------------------------------------------------
__global__ __launch_bounds__(256) void split_x(const float* __restrict__ x,
        unsigned short* __restrict__ xh, unsigned short* __restrict__ xl, int n4) {
    int i = blockIdx.x * 256 + threadIdx.x;
    if (i >= n4) return;
    float4 v = ((const float4*)x)[i];
    float f[4] = {v.x, v.y, v.z, v.w};
#pragma unroll
    for (int j = 0; j < 4; ++j) {
        unsigned short h = f2bf(f[j]);
        xh[i * 4 + j] = h;
        xl[i * 4 + j] = f2bf(f[j] - bf2f(h));
    }
}

// W [K][N] fp32 -> WT hi/lo [N][K] bf16 (transposed, split)
__global__ __launch_bounds__(256) void transpose_split(const float* __restrict__ w,
        unsigned short* __restrict__ wth, unsigned short* __restrict__ wtl,
        int K, int N) {
    __shared__ float tile[64][65];
    const int k0 = blockIdx.y * 64, n0 = blockIdx.x * 64;
    const int t = threadIdx.x;
#pragma unroll
    for (int i = 0; i < 16; ++i) {
        int idx = t + i * 256;
        int r = idx >> 6, c = idx & 63;
        tile[r][c] = w[(size_t)(k0 + r) * N + n0 + c];
    }
    __syncthreads();
#pragma unroll
    for (int i = 0; i < 16; ++i) {
        int idx = t + i * 256;
        int r = idx >> 6, c = idx & 63;    // r = n-local, c = k-local
        float v = tile[c][r];
        unsigned short h = f2bf(v);
        wth[(size_t)(n0 + r) * K + k0 + c] = h;
        wtl[(size_t)(n0 + r) * K + k0 + c] = f2bf(v - bf2f(h));
    }
}

// ---------------------------------------------------------------------------
// QKV GEMM: [8192,384] @ [384,1152] + bias, hi/lo bf16 MFMA, epilogue scatters
// q (x0.125, split), k, v(transposed [g][64][1024]) as bf16 hi/lo.
// ---------------------------------------------------------------------------
__global__ __launch_bounds__(256) void qkv_gemm_mfma(
        const unsigned short* __restrict__ xh, const unsigned short* __restrict__ xl,
        const unsigned short* __restrict__ wth, const unsigned short* __restrict__ wtl,
        const float* __restrict__ bias,
        unsigned short* __restrict__ qh, unsigned short* __restrict__ ql,
        unsigned short* __restrict__ kh, unsigned short* __restrict__ kl,
        unsigned short* __restrict__ vth, unsigned short* __restrict__ vtl) {
    __shared__ unsigned short Ah[64 * 32], Al[64 * 32], Bh[64 * 32], Bl[64 * 32];
    const int t = threadIdx.x;
    const int lane = t & 63, wid = t >> 6;
    const int C = lane & 15, G = lane >> 4;
    const int row0 = blockIdx.y * 64, col0 = blockIdx.x * 64;
    f32x4 acc[4] = {};
    for (int kb = 0; kb < 12; ++kb) {
        __syncthreads();
        {
            int r = t >> 2, c8 = t & 3;
            int lo = r * 32 + c8 * 8;
            size_t ga = (size_t)(row0 + r) * 384 + kb * 32 + c8 * 8;
            size_t gb = (size_t)(col0 + r) * 384 + kb * 32 + c8 * 8;
            *(bf16x8*)(Ah + lo) = *(const bf16x8*)(xh + ga);
            *(bf16x8*)(Al + lo) = *(const bf16x8*)(xl + ga);
            *(bf16x8*)(Bh + lo) = *(const bf16x8*)(wth + gb);
            *(bf16x8*)(Bl + lo) = *(const bf16x8*)(wtl + gb);
        }
        __syncthreads();
        bf16x8 ah = *(const bf16x8*)(Ah + (wid * 16 + C) * 32 + G * 8);
        bf16x8 al = *(const bf16x8*)(Al + (wid * 16 + C) * 32 + G * 8);
#pragma unroll
        for (int s = 0; s < 4; ++s) {
            bf16x8 bh = *(const bf16x8*)(Bh + (s * 16 + C) * 32 + G * 8);
            bf16x8 bl = *(const bf16x8*)(Bl + (s * 16 + C) * 32 + G * 8);
            acc[s] = MFMA(ah, bh, acc[s]);
            acc[s] = MFMA(ah, bl, acc[s]);
            acc[s] = MFMA(al, bh, acc[s]);
        }
    }
#pragma unroll
    for (int s = 0; s < 4; ++s) {
        int n = col0 + s * 16 + C;
        float bv = bias[n];
        int tsel = n / 384;
        int rem = n - tsel * 384;
        int head = rem >> 6, d = rem & 63;
#pragma unroll
        for (int r = 0; r < 4; ++r) {
            int m = row0 + wid * 16 + 4 * G + r;
            int b = m >> 10, hw = m & 1023;
            int g = b * 6 + head;
            float val = acc[s][r] + bv;
            if (tsel == 0) val *= 0.125f;
            unsigned short h = f2bf(val);
            unsigned short l = f2bf(val - bf2f(h));
            if (tsel == 2) {
                size_t o = ((size_t)g * 64 + d) * 1024 + hw;
                vth[o] = h; vtl[o] = l;
            } else {
                size_t o = ((size_t)g * 1024 + hw) * 64 + d;
                if (tsel == 0) { qh[o] = h; ql[o] = l; }
                else           { kh[o] = h; kl[o] = l; }
            }
        }
    }
}

// ---------------------------------------------------------------------------
// rel_h / rel_w from bf16 hi/lo q (scaled by 0.125 -> multiply result by 8)
// ---------------------------------------------------------------------------
__global__ __launch_bounds__(256) void rel_kernel(
        const unsigned short* __restrict__ qh, const unsigned short* __restrict__ ql,
        const float* __restrict__ rph, const float* __restrict__ rpw,
        unsigned short* __restrict__ relh, unsigned short* __restrict__ relw) {
    __shared__ float qs[32][65];
    __shared__ float Rl[32][65];
    const int g = blockIdx.x, pos = blockIdx.y, mode = blockIdx.z;
    const int t = threadIdx.x;
    const float* rp = (mode == 0) ? rph : rpw;
    for (int i = t; i < 2048; i += 256) {
        int r = i >> 6, d = i & 63;
        int hw = (mode == 0) ? (pos * 32 + r) : (r * 32 + pos);
        size_t o = ((size_t)g * 1024 + hw) * 64 + d;
        qs[r][d] = bf2f(qh[o]) + bf2f(ql[o]);
    }
    for (int i = t; i < 2048; i += 256) {
        int r = i >> 6, d = i & 63;
        Rl[r][d] = rp[(pos - r + 31) * 64 + d];
    }
    __syncthreads();
#pragma unroll
    for (int i = 0; i < 4; ++i) {
        int o = t + i * 256;
        int other = o >> 5, idx = o & 31;
        float s = 0.f;
#pragma unroll
        for (int d = 0; d < 64; ++d) s = fmaf(qs[other][d], Rl[idx][d], s);
        s *= 8.0f;
        if (mode == 0) relh[((size_t)g * 1024 + pos * 32 + other) * 32 + idx] = f2bf(s);
        else           relw[((size_t)g * 1024 + other * 32 + pos) * 32 + idx] = f2bf(s);
    }
}

// ---------------------------------------------------------------------------
// Flash attention, MFMA. 4 waves x 16 q-rows, KVBLK=64.
// ---------------------------------------------------------------------------
__global__ __launch_bounds__(256) void attn_mfma(
        const unsigned short* __restrict__ qh, const unsigned short* __restrict__ ql,
        const unsigned short* __restrict__ kh_g, const unsigned short* __restrict__ kl_g,
        const unsigned short* __restrict__ vth_g, const unsigned short* __restrict__ vtl_g,
        const unsigned short* __restrict__ relh, const unsigned short* __restrict__ relw,
        unsigned short* __restrict__ atth, unsigned short* __restrict__ attl) {
    __shared__ unsigned short Kh[64 * 64], Kl[64 * 64], Vh[64 * 64], Vl[64 * 64];
    __shared__ unsigned short Pl[4][16 * 64];
    const int t = threadIdx.x;
    const int lane = t & 63, wid = t >> 6;
    const int C = lane & 15, G = lane >> 4;
    const int qb = blockIdx.x, g = blockIdx.y;
    const int qtile = qb * 64 + wid * 16;

    // Q fragments (hoisted, global)
    bf16x8 qfh[2], qfl[2];
    {
        size_t qo = ((size_t)g * 1024 + qtile + C) * 64;
        qfh[0] = *(const bf16x8*)(qh + qo + G * 8);
        qfh[1] = *(const bf16x8*)(qh + qo + 32 + G * 8);
        qfl[0] = *(const bf16x8*)(ql + qo + G * 8);
        qfl[1] = *(const bf16x8*)(ql + qo + 32 + G * 8);
    }
    // rel_w hoisted (kw = C for even 16-blocks, 16+C for odd)
    float rw0[4], rw1[4];
    const size_t relbase = (size_t)g * 1024 + qtile + 4 * G;
#pragma unroll
    for (int r = 0; r < 4; ++r) {
        rw0[r] = bf2f(relw[(relbase + r) * 32 + C]);
        rw1[r] = bf2f(relw[(relbase + r) * 32 + 16 + C]);
    }
    f32x4 O[4] = {};
    float m_[4], l_[4];
#pragma unroll
    for (int r = 0; r < 4; ++r) { m_[r] = -1e30f; l_[r] = 0.f; }
    unsigned short* Pw = Pl[wid];

    for (int kb = 0; kb < 16; ++kb) {
        __syncthreads();
#pragma unroll
        for (int i = 0; i < 2; ++i) {   // stage K hi/lo, V^T hi/lo (swizzled)
            int idx = t + i * 256;
            int r = idx >> 3, c8 = idx & 7;
            int lo = r * 128 + ((c8 * 16) ^ ((r & 7) << 4));
            size_t gk = ((size_t)g * 1024 + kb * 64 + r) * 64 + c8 * 8;
            size_t gv = ((size_t)g * 64 + r) * 1024 + kb * 64 + c8 * 8;
            *(bf16x8*)((char*)Kh + lo) = *(const bf16x8*)(kh_g + gk);
            *(bf16x8*)((char*)Kl + lo) = *(const bf16x8*)(kl_g + gk);
            *(bf16x8*)((char*)Vh + lo) = *(const bf16x8*)(vth_g + gv);
            *(bf16x8*)((char*)Vl + lo) = *(const bf16x8*)(vtl_g + gv);
        }
        __syncthreads();
        // ---- QK^T ----
        f32x4 S[4] = {};
#pragma unroll
        for (int ks = 0; ks < 2; ++ks) {
#pragma unroll
            for (int s = 0; s < 4; ++s) {
                int row = s * 16 + C;
                int off = row * 128 + ((ks * 64 + G * 16) ^ ((row & 7) << 4));
                bf16x8 bh = *(const bf16x8*)((char*)Kh + off);
                bf16x8 bl = *(const bf16x8*)((char*)Kl + off);
                S[s] = MFMA(qfh[ks], bh, S[s]);
                S[s] = MFMA(qfh[ks], bl, S[s]);
                S[s] = MFMA(qfl[ks], bh, S[s]);
            }
        }
        // ---- rel terms ----
#pragma unroll
        for (int r = 0; r < 4; ++r) {
            float rh0 = bf2f(relh[(relbase + r) * 32 + 2 * kb]);
            float rh1 = bf2f(relh[(relbase + r) * 32 + 2 * kb + 1]);
            S[0][r] += rh0 + rw0[r];
            S[1][r] += rh0 + rw1[r];
            S[2][r] += rh1 + rw0[r];
            S[3][r] += rh1 + rw1[r];
        }
        // ---- online softmax ----
        float corr[4];
#pragma unroll
        for (int r = 0; r < 4; ++r) {
            float mt = fmaxf(fmaxf(S[0][r], S[1][r]), fmaxf(S[2][r], S[3][r]));
            mt = fmaxf(mt, __shfl_xor(mt, 1));
            mt = fmaxf(mt, __shfl_xor(mt, 2));
            mt = fmaxf(mt, __shfl_xor(mt, 4));
            mt = fmaxf(mt, __shfl_xor(mt, 8));
            float mn = fmaxf(m_[r], mt);
            corr[r] = __expf(m_[r] - mn);
            m_[r] = mn;
        }
#pragma unroll
        for (int s = 0; s < 4; ++s)
#pragma unroll
            for (int r = 0; r < 4; ++r)
                S[s][r] = __expf(S[s][r] - m_[r]);
#pragma unroll
        for (int r = 0; r < 4; ++r) {
            l_[r] = l_[r] * corr[r] + S[0][r] + S[1][r] + S[2][r] + S[3][r];
            O[0][r] *= corr[r]; O[1][r] *= corr[r];
            O[2][r] *= corr[r]; O[3][r] *= corr[r];
        }
        // ---- P -> LDS (bf16, per-wave buffer, swizzled) ----
#pragma unroll
        for (int s = 0; s < 4; ++s)
#pragma unroll
            for (int r = 0; r < 4; ++r) {
                int row = 4 * G + r;
                int bo = row * 128 + ((((s * 16 + C) * 2)) ^ ((row & 7) << 4));
                *(unsigned short*)((char*)Pw + bo) = f2bf(S[s][r]);
            }
        // ---- PV ----
#pragma unroll
        for (int ks = 0; ks < 2; ++ks) {
            int aoff = C * 128 + ((ks * 64 + G * 16) ^ ((C & 7) << 4));
            bf16x8 pa = *(const bf16x8*)((char*)Pw + aoff);
#pragma unroll
            for (int s = 0; s < 4; ++s) {
                int vrow = s * 16 + C;
                int voff = vrow * 128 + ((ks * 64 + G * 16) ^ ((vrow & 7) << 4));
                bf16x8 vh = *(const bf16x8*)((char*)Vh + voff);
                bf16x8 vl = *(const bf16x8*)((char*)Vl + voff);
                O[s] = MFMA(pa, vh, O[s]);
                O[s] = MFMA(pa, vl, O[s]);
            }
        }
    }
    // ---- epilogue: reduce l, normalize, split to bf16 hi/lo ----
    const int b = g / 6, head = g - b * 6;
#pragma unroll
    for (int r = 0; r < 4; ++r) {
        float lv = l_[r];
        lv += __shfl_xor(lv, 1);
        lv += __shfl_xor(lv, 2);
        lv += __shfl_xor(lv, 4);
        lv += __shfl_xor(lv, 8);
        float inv = 1.0f / lv;
        int token = qtile + 4 * G + r;
        size_t ob = ((size_t)b * 1024 + token) * 384 + head * 64;
#pragma unroll
        for (int s = 0; s < 4; ++s) {
            float o = O[s][r] * inv;
            unsigned short h = f2bf(o);
            unsigned short l2 = f2bf(o - bf2f(h));
            atth[ob + s * 16 + C] = h;
            attl[ob + s * 16 + C] = l2;
        }
    }
}

// ---------------------------------------------------------------------------
// Output projection: [8192,384] @ [384,384] + bias -> fp32 out
// ---------------------------------------------------------------------------
__global__ __launch_bounds__(256) void proj_gemm_mfma(
        const unsigned short* __restrict__ ah_g, const unsigned short* __restrict__ al_g,
        const unsigned short* __restrict__ bth, const unsigned short* __restrict__ btl,
        const float* __restrict__ bias, float* __restrict__ out) {
    __shared__ unsigned short Ah[64 * 32], Al[64 * 32], Bh[64 * 32], Bl[64 * 32];
    const int t = threadIdx.x;
    const int lane = t & 63, wid = t >> 6;
    const int C = lane & 15, G = lane >> 4;
    const int row0 = blockIdx.y * 64, col0 = blockIdx.x * 64;
    f32x4 acc[4] = {};
    for (int kb = 0; kb < 12; ++kb) {
        __syncthreads();
        {
            int r = t >> 2, c8 = t & 3;
            int lo = r * 32 + c8 * 8;
            size_t ga = (size_t)(row0 + r) * 384 + kb * 32 + c8 * 8;
            size_t gb = (size_t)(col0 + r) * 384 + kb * 32 + c8 * 8;
            *(bf16x8*)(Ah + lo) = *(const bf16x8*)(ah_g + ga);
            *(bf16x8*)(Al + lo) = *(const bf16x8*)(al_g + ga);
            *(bf16x8*)(Bh + lo) = *(const bf16x8*)(bth + gb);
            *(bf16x8*)(Bl + lo) = *(const bf16x8*)(btl + gb);
        }
        __syncthreads();
        bf16x8 ah = *(const bf16x8*)(Ah + (wid * 16 + C) * 32 + G * 8);
        bf16x8 al = *(const bf16x8*)(Al + (wid * 16 + C) * 32 + G * 8);
#pragma unroll
        for (int s = 0; s < 4; ++s) {
            bf16x8 bh = *(const bf16x8*)(Bh + (s * 16 + C) * 32 + G * 8);
            bf16x8 bl = *(const bf16x8*)(Bl + (s * 16 + C) * 32 + G * 8);
            acc[s] = MFMA(ah, bh, acc[s]);
            acc[s] = MFMA(ah, bl, acc[s]);
            acc[s] = MFMA(al, bh, acc[s]);
        }
    }
#pragma unroll
    for (int s = 0; s < 4; ++s) {
        int n = col0 + s * 16 + C;
        float bv = bias[n];
#pragma unroll
        for (int r = 0; r < 4; ++r) {
            int m = row0 + wid * 16 + 4 * G + r;
            out[(size_t)m * 384 + n] = acc[s][r] + bv;
        }
    }
}

extern "C" void kernel_launch(void* const* d_in, const int* in_sizes, int n_in,
                              void* d_out, int out_size, void* d_ws, size_t ws_size,
                              hipStream_t stream) {
    const float* x      = (const float*)d_in[0];
    const float* qkv_w  = (const float*)d_in[1];
    const float* qkv_b  = (const float*)d_in[2];
    const float* proj_w = (const float*)d_in[3];
    const float* proj_b = (const float*)d_in[4];
    const float* rph    = (const float*)d_in[5];
    const float* rpw    = (const float*)d_in[6];
    char* ws = (char*)d_ws;

    unsigned short* QHI  = (unsigned short*)(ws + WS_QHI);
    unsigned short* QLO  = (unsigned short*)(ws + WS_QLO);
    unsigned short* KHI  = (unsigned short*)(ws + WS_KHI);
    unsigned short* KLO  = (unsigned short*)(ws + WS_KLO);
    unsigned short* VTHI = (unsigned short*)(ws + WS_VTHI);
    unsigned short* VTLO = (unsigned short*)(ws + WS_VTLO);
    unsigned short* RELH = (unsigned short*)(ws + WS_RELH);
    unsigned short* RELW = (unsigned short*)(ws + WS_RELW);
    unsigned short* WTH  = (unsigned short*)(ws + WS_WTH);
    unsigned short* WTL  = (unsigned short*)(ws + WS_WTL);
    unsigned short* PWTH = (unsigned short*)(ws + WS_PWTH);
    unsigned short* PWTL = (unsigned short*)(ws + WS_PWTL);
    unsigned short* XHI  = (unsigned short*)(ws + WS_XHI);
    unsigned short* XLO  = (unsigned short*)(ws + WS_XLO);
    unsigned short* ATTH = XHI;   // reuse (x consumed before attn writes)
    unsigned short* ATTL = XLO;

    split_x<<<3072, 256, 0, stream>>>(x, XHI, XLO, 786432);
    transpose_split<<<dim3(18, 6), 256, 0, stream>>>(qkv_w, WTH, WTL, 384, 1152);
    transpose_split<<<dim3(6, 6), 256, 0, stream>>>(proj_w, PWTH, PWTL, 384, 384);
    qkv_gemm_mfma<<<dim3(18, 128), 256, 0, stream>>>(XHI, XLO, WTH, WTL, qkv_b,
                                                     QHI, QLO, KHI, KLO, VTHI, VTLO);
    rel_kernel<<<dim3(48, 32, 2), 256, 0, stream>>>(QHI, QLO, rph, rpw, RELH, RELW);
    attn_mfma<<<dim3(16, 48), 256, 0, stream>>>(QHI, QLO, KHI, KLO, VTHI, VTLO,
                                                RELH, RELW, ATTH, ATTL);
    proj_gemm_mfma<<<dim3(6, 128), 256, 0, stream>>>(ATTH, ATTL, PWTH, PWTL,
                                                     proj_b, (float*)d_out);
}

// Round 3
// 140.135 us; speedup vs baseline: 5.8978x; 1.3177x over previous
//
#include <hip/hip_runtime.h>

typedef __attribute__((ext_vector_type(8))) short bf16x8;
typedef __attribute__((ext_vector_type(4))) float f32x4;

#define MFMA(a, b, c) __builtin_amdgcn_mfma_f32_16x16x32_bf16((a), (b), (c), 0, 0, 0)

__device__ __forceinline__ unsigned short f2bf(float f) {
    union { float f; unsigned u; } v; v.f = f;
    unsigned r = v.u + 0x7FFFu + ((v.u >> 16) & 1u);
    return (unsigned short)(r >> 16);
}
__device__ __forceinline__ float bf2f(unsigned short h) {
    union { unsigned u; float f; } v; v.u = ((unsigned)h) << 16;
    return v.f;
}
// async global->LDS, 16B per lane, dest = ldsbase + lane*16 (wave-uniform base)
__device__ __forceinline__ void gload16(const void* g, void* l) {
    __builtin_amdgcn_global_load_lds(
        (const __attribute__((address_space(1))) void*)g,
        (__attribute__((address_space(3))) void*)l, 16, 0, 0);
}

// ---------------------------------------------------------------------------
// Workspace layout (bytes). ATT arrays reuse the X region.
// ---------------------------------------------------------------------------
#define WS_QHI   0
#define WS_QLO   6291456
#define WS_KHI   12582912
#define WS_KLO   18874368
#define WS_VTHI  25165824
#define WS_RELH  37748736
#define WS_RELW  40894464
#define WS_WTH   44040192
#define WS_WTL   44924928
#define WS_PWTH  45809664
#define WS_PWTL  46104576
#define WS_XHI   46399488
#define WS_XLO   52690944
// end 58982400 bytes (56.25 MB)

// ---------------------------------------------------------------------------
// Prep: split fp32 -> bf16 hi/lo
// ---------------------------------------------------------------------------
__global__ __launch_bounds__(256) void split_x(const float* __restrict__ x,
        unsigned short* __restrict__ xh, unsigned short* __restrict__ xl, int n4) {
    int i = blockIdx.x * 256 + threadIdx.x;
    if (i >= n4) return;
    float4 v = ((const float4*)x)[i];
    float f[4] = {v.x, v.y, v.z, v.w};
#pragma unroll
    for (int j = 0; j < 4; ++j) {
        unsigned short h = f2bf(f[j]);
        xh[i * 4 + j] = h;
        xl[i * 4 + j] = f2bf(f[j] - bf2f(h));
    }
}

// W [K][N] fp32 -> WT hi/lo [N][K] bf16 (transposed, split)
__global__ __launch_bounds__(256) void transpose_split(const float* __restrict__ w,
        unsigned short* __restrict__ wth, unsigned short* __restrict__ wtl,
        int K, int N) {
    __shared__ float tile[64][65];
    const int k0 = blockIdx.y * 64, n0 = blockIdx.x * 64;
    const int t = threadIdx.x;
#pragma unroll
    for (int i = 0; i < 16; ++i) {
        int idx = t + i * 256;
        int r = idx >> 6, c = idx & 63;
        tile[r][c] = w[(size_t)(k0 + r) * N + n0 + c];
    }
    __syncthreads();
#pragma unroll
    for (int i = 0; i < 16; ++i) {
        int idx = t + i * 256;
        int r = idx >> 6, c = idx & 63;    // r = n-local, c = k-local
        float v = tile[c][r];
        unsigned short h = f2bf(v);
        wth[(size_t)(n0 + r) * K + k0 + c] = h;
        wtl[(size_t)(n0 + r) * K + k0 + c] = f2bf(v - bf2f(h));
    }
}

// ---------------------------------------------------------------------------
// QKV GEMM: [8192,384] @ [384,1152] + bias, hi/lo bf16 MFMA, epilogue scatters
// q (x0.125, split), k (split), v (transposed [g][64][1024], hi only).
// ---------------------------------------------------------------------------
__global__ __launch_bounds__(256) void qkv_gemm_mfma(
        const unsigned short* __restrict__ xh, const unsigned short* __restrict__ xl,
        const unsigned short* __restrict__ wth, const unsigned short* __restrict__ wtl,
        const float* __restrict__ bias,
        unsigned short* __restrict__ qh, unsigned short* __restrict__ ql,
        unsigned short* __restrict__ kh, unsigned short* __restrict__ kl,
        unsigned short* __restrict__ vth) {
    __shared__ unsigned short Ah[64 * 32], Al[64 * 32], Bh[64 * 32], Bl[64 * 32];
    const int t = threadIdx.x;
    const int lane = t & 63, wid = t >> 6;
    const int C = lane & 15, G = lane >> 4;
    const int row0 = blockIdx.y * 64, col0 = blockIdx.x * 64;
    f32x4 acc[4] = {};
    for (int kb = 0; kb < 12; ++kb) {
        __syncthreads();
        {
            int r = t >> 2, c8 = t & 3;
            int lo = r * 32 + c8 * 8;
            size_t ga = (size_t)(row0 + r) * 384 + kb * 32 + c8 * 8;
            size_t gb = (size_t)(col0 + r) * 384 + kb * 32 + c8 * 8;
            *(bf16x8*)(Ah + lo) = *(const bf16x8*)(xh + ga);
            *(bf16x8*)(Al + lo) = *(const bf16x8*)(xl + ga);
            *(bf16x8*)(Bh + lo) = *(const bf16x8*)(wth + gb);
            *(bf16x8*)(Bl + lo) = *(const bf16x8*)(wtl + gb);
        }
        __syncthreads();
        bf16x8 ah = *(const bf16x8*)(Ah + (wid * 16 + C) * 32 + G * 8);
        bf16x8 al = *(const bf16x8*)(Al + (wid * 16 + C) * 32 + G * 8);
#pragma unroll
        for (int s = 0; s < 4; ++s) {
            bf16x8 bh = *(const bf16x8*)(Bh + (s * 16 + C) * 32 + G * 8);
            bf16x8 bl = *(const bf16x8*)(Bl + (s * 16 + C) * 32 + G * 8);
            acc[s] = MFMA(ah, bh, acc[s]);
            acc[s] = MFMA(ah, bl, acc[s]);
            acc[s] = MFMA(al, bh, acc[s]);
        }
    }
#pragma unroll
    for (int s = 0; s < 4; ++s) {
        int n = col0 + s * 16 + C;
        float bv = bias[n];
        int tsel = n / 384;
        int rem = n - tsel * 384;
        int head = rem >> 6, d = rem & 63;
#pragma unroll
        for (int r = 0; r < 4; ++r) {
            int m = row0 + wid * 16 + 4 * G + r;
            int b = m >> 10, hw = m & 1023;
            int g = b * 6 + head;
            float val = acc[s][r] + bv;
            if (tsel == 0) val *= 0.125f;
            unsigned short h = f2bf(val);
            if (tsel == 2) {
                vth[((size_t)g * 64 + d) * 1024 + hw] = h;
            } else {
                size_t o = ((size_t)g * 1024 + hw) * 64 + d;
                unsigned short l = f2bf(val - bf2f(h));
                if (tsel == 0) { qh[o] = h; ql[o] = l; }
                else           { kh[o] = h; kl[o] = l; }
            }
        }
    }
}

// ---------------------------------------------------------------------------
// rel_h / rel_w via MFMA. Block = (pos, g-chunk of 8, mode); 256 A-rows x 32 k.
// q is pre-scaled by 0.125 -> result x8 (exact pow2). hi-only precision.
// ---------------------------------------------------------------------------
__global__ __launch_bounds__(256) void rel_mfma(
        const unsigned short* __restrict__ qh,
        const float* __restrict__ rph, const float* __restrict__ rpw,
        unsigned short* __restrict__ relh, unsigned short* __restrict__ relw) {
    __shared__ unsigned short Bs[32 * 64];
    const int t = threadIdx.x;
    const int lane = t & 63, wid = t >> 6;
    const int C = lane & 15, G = lane >> 4;
    const int pos = blockIdx.x;
    const int g0 = blockIdx.y * 8;
    const int mode = blockIdx.z;
    const float* rp = (mode == 0) ? rph : rpw;
    {   // stage B[k][d] = bf16(rp[pos+31-k][d]), XOR-swizzled 128B rows
        int k = t >> 3, d8 = t & 7;
        const float* src = rp + (size_t)(pos + 31 - k) * 64 + d8 * 8;
        float4 f0 = *(const float4*)src;
        float4 f1 = *(const float4*)(src + 4);
        unsigned short hv[8] = { f2bf(f0.x), f2bf(f0.y), f2bf(f0.z), f2bf(f0.w),
                                 f2bf(f1.x), f2bf(f1.y), f2bf(f1.z), f2bf(f1.w) };
        int bo = k * 128 + ((d8 * 16) ^ ((k & 7) << 4));
        *(bf16x8*)((char*)Bs + bo) = *(bf16x8*)hv;
    }
    __syncthreads();
    bf16x8 bf[2][2];
#pragma unroll
    for (int s = 0; s < 2; ++s)
#pragma unroll
        for (int ks = 0; ks < 2; ++ks) {
            int row = s * 16 + C;
            int off = row * 128 + ((ks * 64 + G * 16) ^ ((row & 7) << 4));
            bf[s][ks] = *(const bf16x8*)((char*)Bs + off);
        }
#pragma unroll
    for (int ib = 0; ib < 4; ++ib) {
        int arow = ib * 64 + wid * 16 + C;
        int gi = arow >> 5, w = arow & 31;
        int hw = (mode == 0) ? (pos * 32 + w) : (w * 32 + pos);
        const unsigned short* qrow = qh + ((size_t)(g0 + gi) * 1024 + hw) * 64;
        bf16x8 a0 = *(const bf16x8*)(qrow + G * 8);
        bf16x8 a1 = *(const bf16x8*)(qrow + 32 + G * 8);
        f32x4 acc[2] = {};
#pragma unroll
        for (int s = 0; s < 2; ++s) {
            acc[s] = MFMA(a0, bf[s][0], acc[s]);
            acc[s] = MFMA(a1, bf[s][1], acc[s]);
        }
        unsigned short* dst = (mode == 0) ? relh : relw;
#pragma unroll
        for (int s = 0; s < 2; ++s)
#pragma unroll
            for (int rr = 0; rr < 4; ++rr) {
                int orow = ib * 64 + wid * 16 + 4 * G + rr;
                int ogi = orow >> 5, ow = orow & 31;
                int ohw = (mode == 0) ? (pos * 32 + ow) : (ow * 32 + pos);
                dst[((size_t)(g0 + ogi) * 1024 + ohw) * 32 + s * 16 + C] =
                    f2bf(acc[s][rr] * 8.0f);
            }
    }
}

// ---------------------------------------------------------------------------
// Flash attention, MFMA. 4 waves x 16 q-rows, KVBLK=64.
// Staging via global_load_lds (pre-swizzled source, linear LDS dest).
// ---------------------------------------------------------------------------
__global__ __launch_bounds__(256) void attn_mfma(
        const unsigned short* __restrict__ qh, const unsigned short* __restrict__ ql,
        const unsigned short* __restrict__ kh_g, const unsigned short* __restrict__ kl_g,
        const unsigned short* __restrict__ vth_g,
        const unsigned short* __restrict__ relh, const unsigned short* __restrict__ relw,
        unsigned short* __restrict__ atth, unsigned short* __restrict__ attl) {
    __shared__ unsigned short Kh[64 * 64], Kl[64 * 64], Vh[64 * 64];
    __shared__ unsigned short Pl[4][16 * 64];
    const int t = threadIdx.x;
    const int lane = t & 63, wid = t >> 6;
    const int C = lane & 15, G = lane >> 4;
    // XCD-aware swizzle: 768 blocks, 96 per XCD -> each XCD owns 6 whole heads
    const int bid = blockIdx.x;
    const int wgid = (bid & 7) * 96 + (bid >> 3);
    const int g = wgid >> 4, qb = wgid & 15;
    const int qtile = qb * 64 + wid * 16;

    // ---- staging source addresses (static per lane; advance per kb) ----
    const int c0 = wid * 2;                         // this wave's 2 chunks
    const int rsub = lane >> 3;                     // row-within-chunk
    const int cbyt = ((lane & 7) << 4) ^ (rsub << 4);  // pre-swizzled col bytes
    const char* khp = (const char*)(kh_g + (size_t)g * 65536) + (c0 * 8 + rsub) * 128 + cbyt;
    const char* klp = (const char*)(kl_g + (size_t)g * 65536) + (c0 * 8 + rsub) * 128 + cbyt;
    const char* vhp = (const char*)(vth_g + (size_t)g * 65536) + (c0 * 8 + rsub) * 2048 + cbyt;
    char* ldsKh = (char*)Kh + c0 * 1024;
    char* ldsKl = (char*)Kl + c0 * 1024;
    char* ldsVh = (char*)Vh + c0 * 1024;

    // ---- Q fragments (hoisted) ----
    bf16x8 qfh[2], qfl[2];
    {
        size_t qo = ((size_t)g * 1024 + qtile + C) * 64;
        qfh[0] = *(const bf16x8*)(qh + qo + G * 8);
        qfh[1] = *(const bf16x8*)(qh + qo + 32 + G * 8);
        qfl[0] = *(const bf16x8*)(ql + qo + G * 8);
        qfl[1] = *(const bf16x8*)(ql + qo + 32 + G * 8);
    }
    float rw0[4], rw1[4];
    const size_t relbase = (size_t)g * 1024 + qtile + 4 * G;
#pragma unroll
    for (int r = 0; r < 4; ++r) {
        rw0[r] = bf2f(relw[(relbase + r) * 32 + C]);
        rw1[r] = bf2f(relw[(relbase + r) * 32 + 16 + C]);
    }
    f32x4 O[4] = {};
    float m_[4], l_[4];
#pragma unroll
    for (int r = 0; r < 4; ++r) { m_[r] = -1e30f; l_[r] = 0.f; }
    unsigned short* Pw = Pl[wid];

    for (int kb = 0; kb < 16; ++kb) {
        __syncthreads();                 // prev-iter LDS reads done
        gload16(khp, ldsKh);
        gload16(khp + 1024, ldsKh + 1024);
        gload16(klp, ldsKl);
        gload16(klp + 1024, ldsKl + 1024);
        gload16(vhp, ldsVh);
        gload16(vhp + 16384, ldsVh + 1024);
        khp += 8192; klp += 8192; vhp += 128;
        __syncthreads();                 // drains vmcnt -> tile ready
        // ---- QK^T (3-term hi/lo) ----
        f32x4 S[4] = {};
#pragma unroll
        for (int ks = 0; ks < 2; ++ks) {
#pragma unroll
            for (int s = 0; s < 4; ++s) {
                int row = s * 16 + C;
                int off = row * 128 + ((ks * 64 + G * 16) ^ ((row & 7) << 4));
                bf16x8 bh = *(const bf16x8*)((char*)Kh + off);
                bf16x8 bl = *(const bf16x8*)((char*)Kl + off);
                S[s] = MFMA(qfh[ks], bh, S[s]);
                S[s] = MFMA(qfh[ks], bl, S[s]);
                S[s] = MFMA(qfl[ks], bh, S[s]);
            }
        }
        // ---- rel terms ----
#pragma unroll
        for (int r = 0; r < 4; ++r) {
            float rh0 = bf2f(relh[(relbase + r) * 32 + 2 * kb]);
            float rh1 = bf2f(relh[(relbase + r) * 32 + 2 * kb + 1]);
            S[0][r] += rh0 + rw0[r];
            S[1][r] += rh0 + rw1[r];
            S[2][r] += rh1 + rw0[r];
            S[3][r] += rh1 + rw1[r];
        }
        // ---- online softmax ----
        float corr[4];
#pragma unroll
        for (int r = 0; r < 4; ++r) {
            float mt = fmaxf(fmaxf(S[0][r], S[1][r]), fmaxf(S[2][r], S[3][r]));
            mt = fmaxf(mt, __shfl_xor(mt, 1));
            mt = fmaxf(mt, __shfl_xor(mt, 2));
            mt = fmaxf(mt, __shfl_xor(mt, 4));
            mt = fmaxf(mt, __shfl_xor(mt, 8));
            float mn = fmaxf(m_[r], mt);
            corr[r] = __expf(m_[r] - mn);
            m_[r] = mn;
        }
#pragma unroll
        for (int s = 0; s < 4; ++s)
#pragma unroll
            for (int r = 0; r < 4; ++r)
                S[s][r] = __expf(S[s][r] - m_[r]);
#pragma unroll
        for (int r = 0; r < 4; ++r) {
            l_[r] = l_[r] * corr[r] + S[0][r] + S[1][r] + S[2][r] + S[3][r];
            O[0][r] *= corr[r]; O[1][r] *= corr[r];
            O[2][r] *= corr[r]; O[3][r] *= corr[r];
        }
        // ---- P -> LDS (bf16, per-wave buffer, swizzled) ----
#pragma unroll
        for (int s = 0; s < 4; ++s)
#pragma unroll
            for (int r = 0; r < 4; ++r) {
                int row = 4 * G + r;
                int bo = row * 128 + ((((s * 16 + C) * 2)) ^ ((row & 7) << 4));
                *(unsigned short*)((char*)Pw + bo) = f2bf(S[s][r]);
            }
        // ---- PV (V hi only) ----
#pragma unroll
        for (int ks = 0; ks < 2; ++ks) {
            int aoff = C * 128 + ((ks * 64 + G * 16) ^ ((C & 7) << 4));
            bf16x8 pa = *(const bf16x8*)((char*)Pw + aoff);
#pragma unroll
            for (int s = 0; s < 4; ++s) {
                int vrow = s * 16 + C;
                int voff = vrow * 128 + ((ks * 64 + G * 16) ^ ((vrow & 7) << 4));
                bf16x8 vh = *(const bf16x8*)((char*)Vh + voff);
                O[s] = MFMA(pa, vh, O[s]);
            }
        }
    }
    // ---- epilogue ----
    const int b = g / 6, head = g - b * 6;
#pragma unroll
    for (int r = 0; r < 4; ++r) {
        float lv = l_[r];
        lv += __shfl_xor(lv, 1);
        lv += __shfl_xor(lv, 2);
        lv += __shfl_xor(lv, 4);
        lv += __shfl_xor(lv, 8);
        float inv = 1.0f / lv;
        int token = qtile + 4 * G + r;
        size_t ob = ((size_t)b * 1024 + token) * 384 + head * 64;
#pragma unroll
        for (int s = 0; s < 4; ++s) {
            float o = O[s][r] * inv;
            unsigned short h = f2bf(o);
            unsigned short l2 = f2bf(o - bf2f(h));
            atth[ob + s * 16 + C] = h;
            attl[ob + s * 16 + C] = l2;
        }
    }
}

// ---------------------------------------------------------------------------
// Output projection: [8192,384] @ [384,384] + bias -> fp32 out
// ---------------------------------------------------------------------------
__global__ __launch_bounds__(256) void proj_gemm_mfma(
        const unsigned short* __restrict__ ah_g, const unsigned short* __restrict__ al_g,
        const unsigned short* __restrict__ bth, const unsigned short* __restrict__ btl,
        const float* __restrict__ bias, float* __restrict__ out) {
    __shared__ unsigned short Ah[64 * 32], Al[64 * 32], Bh[64 * 32], Bl[64 * 32];
    const int t = threadIdx.x;
    const int lane = t & 63, wid = t >> 6;
    const int C = lane & 15, G = lane >> 4;
    const int row0 = blockIdx.y * 64, col0 = blockIdx.x * 64;
    f32x4 acc[4] = {};
    for (int kb = 0; kb < 12; ++kb) {
        __syncthreads();
        {
            int r = t >> 2, c8 = t & 3;
            int lo = r * 32 + c8 * 8;
            size_t ga = (size_t)(row0 + r) * 384 + kb * 32 + c8 * 8;
            size_t gb = (size_t)(col0 + r) * 384 + kb * 32 + c8 * 8;
            *(bf16x8*)(Ah + lo) = *(const bf16x8*)(ah_g + ga);
            *(bf16x8*)(Al + lo) = *(const bf16x8*)(al_g + ga);
            *(bf16x8*)(Bh + lo) = *(const bf16x8*)(bth + gb);
            *(bf16x8*)(Bl + lo) = *(const bf16x8*)(btl + gb);
        }
        __syncthreads();
        bf16x8 ah = *(const bf16x8*)(Ah + (wid * 16 + C) * 32 + G * 8);
        bf16x8 al = *(const bf16x8*)(Al + (wid * 16 + C) * 32 + G * 8);
#pragma unroll
        for (int s = 0; s < 4; ++s) {
            bf16x8 bh = *(const bf16x8*)(Bh + (s * 16 + C) * 32 + G * 8);
            bf16x8 bl = *(const bf16x8*)(Bl + (s * 16 + C) * 32 + G * 8);
            acc[s] = MFMA(ah, bh, acc[s]);
            acc[s] = MFMA(ah, bl, acc[s]);
            acc[s] = MFMA(al, bh, acc[s]);
        }
    }
#pragma unroll
    for (int s = 0; s < 4; ++s) {
        int n = col0 + s * 16 + C;
        float bv = bias[n];
#pragma unroll
        for (int r = 0; r < 4; ++r) {
            int m = row0 + wid * 16 + 4 * G + r;
            out[(size_t)m * 384 + n] = acc[s][r] + bv;
        }
    }
}

extern "C" void kernel_launch(void* const* d_in, const int* in_sizes, int n_in,
                              void* d_out, int out_size, void* d_ws, size_t ws_size,
                              hipStream_t stream) {
    const float* x      = (const float*)d_in[0];
    const float* qkv_w  = (const float*)d_in[1];
    const float* qkv_b  = (const float*)d_in[2];
    const float* proj_w = (const float*)d_in[3];
    const float* proj_b = (const float*)d_in[4];
    const float* rph    = (const float*)d_in[5];
    const float* rpw    = (const float*)d_in[6];
    char* ws = (char*)d_ws;

    unsigned short* QHI  = (unsigned short*)(ws + WS_QHI);
    unsigned short* QLO  = (unsigned short*)(ws + WS_QLO);
    unsigned short* KHI  = (unsigned short*)(ws + WS_KHI);
    unsigned short* KLO  = (unsigned short*)(ws + WS_KLO);
    unsigned short* VTHI = (unsigned short*)(ws + WS_VTHI);
    unsigned short* RELH = (unsigned short*)(ws + WS_RELH);
    unsigned short* RELW = (unsigned short*)(ws + WS_RELW);
    unsigned short* WTH  = (unsigned short*)(ws + WS_WTH);
    unsigned short* WTL  = (unsigned short*)(ws + WS_WTL);
    unsigned short* PWTH = (unsigned short*)(ws + WS_PWTH);
    unsigned short* PWTL = (unsigned short*)(ws + WS_PWTL);
    unsigned short* XHI  = (unsigned short*)(ws + WS_XHI);
    unsigned short* XLO  = (unsigned short*)(ws + WS_XLO);
    unsigned short* ATTH = XHI;   // reuse (x consumed before attn writes)
    unsigned short* ATTL = XLO;

    split_x<<<3072, 256, 0, stream>>>(x, XHI, XLO, 786432);
    transpose_split<<<dim3(18, 6), 256, 0, stream>>>(qkv_w, WTH, WTL, 384, 1152);
    transpose_split<<<dim3(6, 6), 256, 0, stream>>>(proj_w, PWTH, PWTL, 384, 384);
    qkv_gemm_mfma<<<dim3(18, 128), 256, 0, stream>>>(XHI, XLO, WTH, WTL, qkv_b,
                                                     QHI, QLO, KHI, KLO, VTHI);
    rel_mfma<<<dim3(32, 6, 2), 256, 0, stream>>>(QHI, rph, rpw, RELH, RELW);
    attn_mfma<<<768, 256, 0, stream>>>(QHI, QLO, KHI, KLO, VTHI,
                                       RELH, RELW, ATTH, ATTL);
    proj_gemm_mfma<<<dim3(6, 128), 256, 0, stream>>>(ATTH, ATTL, PWTH, PWTL,
                                                     proj_b, (float*)d_out);
}